// Round 1
// baseline (1604.551 us; speedup 1.0000x reference)
//
#include <hip/hip_runtime.h>
#include <math.h>

// ---------- small helpers ----------
#define DEVI static __device__ __forceinline__
typedef __bf16 bf16x8 __attribute__((ext_vector_type(8)));
typedef float  f32x4v __attribute__((ext_vector_type(4)));
typedef unsigned short u16;

DEVI float b2f(u16 u){ union{unsigned int i; float f;} v; v.i=((unsigned int)u)<<16; return v.f; }
DEVI u16 f2b(float f){ union{float f; unsigned int i;} v; v.f=f;
                       unsigned int r=v.i+0x7FFFu+((v.i>>16)&1u); return (u16)(r>>16); }

// ---------- fp32 -> bf16 convert ----------
__global__ __launch_bounds__(256) void cvt_f32_bf16(const float* __restrict__ s,
                                                    u16* __restrict__ d, int n){
  int i = (blockIdx.x*256 + threadIdx.x)*4;
  if (i < n){
    float4 v = *(const float4*)(s+i);
    ushort4 o; o.x=f2b(v.x); o.y=f2b(v.y); o.z=f2b(v.z); o.w=f2b(v.w);
    *(ushort4*)(d+i) = o;
  }
}

// ---------- LayerNorm: fp32 row [1024] -> bf16 ----------
__global__ __launch_bounds__(256) void ln_kernel(const float* __restrict__ x,
                                                 const float* __restrict__ w,
                                                 u16* __restrict__ ob){
  const int row = blockIdx.x, tid = threadIdx.x;
  const float* xr = x + (size_t)row*1024;
  float4 v = *(const float4*)(xr + tid*4);
  float s = v.x+v.y+v.z+v.w;
  for(int m=32;m;m>>=1) s += __shfl_xor(s,m);
  __shared__ float r0[4], r1[4];
  const int wid = tid>>6, lane = tid&63;
  if(!lane) r0[wid]=s;
  __syncthreads();
  const float mean = (r0[0]+r0[1]+r0[2]+r0[3])*(1.f/1024.f);
  float d0=v.x-mean,d1=v.y-mean,d2=v.z-mean,d3=v.w-mean;
  float s2 = d0*d0+d1*d1+d2*d2+d3*d3;
  for(int m=32;m;m>>=1) s2 += __shfl_xor(s2,m);
  if(!lane) r1[wid]=s2;
  __syncthreads();
  const float inv = rsqrtf((r1[0]+r1[1]+r1[2]+r1[3])*(1.f/1024.f) + 1e-5f);
  float4 wv = *(const float4*)(w + tid*4);
  ushort4 o; o.x=f2b(d0*inv*wv.x); o.y=f2b(d1*inv*wv.y);
  o.z=f2b(d2*inv*wv.z); o.w=f2b(d3*inv*wv.w);
  *(ushort4*)(ob + (size_t)row*1024 + tid*4) = o;
}

// ---------- RoPE in-place on bf16 q,k rows ----------
__global__ __launch_bounds__(256) void rope_kernel(u16* __restrict__ q, u16* __restrict__ k){
  const int row = blockIdx.x;            // 0..4095  (b*2048 + t)
  const int t = row & 2047;
  u16* qr = q + (size_t)row*1024;
  u16* kr = k + (size_t)row*1024;
  for (int dd = threadIdx.x; dd < 512; dd += 256){
    // inv_freq[j] = 10000^(-j/512) = exp2(-j*log2(1e4)/512)
    const float freq = exp2f(-(float)dd * (13.287712379549449f/512.0f));
    const float ang = (float)t * freq;
    float sn, cs; sincosf(ang, &sn, &cs);
    float a = b2f(qr[dd]), b = b2f(qr[dd+512]);
    qr[dd]     = f2b(a*cs - b*sn);
    qr[dd+512] = f2b(b*cs + a*sn);
    float ka = b2f(kr[dd]), kb = b2f(kr[dd+512]);
    kr[dd]     = f2b(ka*cs - kb*sn);
    kr[dd+512] = f2b(kb*cs + ka*sn);
  }
}

// ---------- causal softmax row kernel: S fp32 [b][t][2048] -> P bf16 ----------
__global__ __launch_bounds__(256) void softmax_kernel(const float* __restrict__ S,
                                                      u16* __restrict__ P){
  const int t = blockIdx.x, b = blockIdx.y, tid = threadIdx.x;
  const float* srow = S + ((size_t)b*2048 + t)*2048;
  u16* prow = P + ((size_t)b*2048 + t)*2048;
  const float scale = 0.03125f;  // 1/sqrt(1024)
  float e[8]; float mx = -INFINITY;
#pragma unroll
  for(int i=0;i<8;i++){
    int c = tid + i*256;
    float v = (c<=t) ? srow[c]*scale : -INFINITY;
    e[i]=v; mx = fmaxf(mx, v);
  }
  for(int m=32;m;m>>=1) mx = fmaxf(mx, __shfl_xor(mx,m));
  __shared__ float r0[4], r1[4];
  const int wid=tid>>6, lane=tid&63;
  if(!lane) r0[wid]=mx;
  __syncthreads();
  mx = fmaxf(fmaxf(r0[0],r0[1]), fmaxf(r0[2],r0[3]));
  float s=0.f;
#pragma unroll
  for(int i=0;i<8;i++){ float v = (e[i]==-INFINITY)?0.f:__expf(e[i]-mx); e[i]=v; s+=v; }
  for(int m=32;m;m>>=1) s += __shfl_xor(s,m);
  if(!lane) r1[wid]=s;
  __syncthreads();
  const float inv = 1.f/(r1[0]+r1[1]+r1[2]+r1[3]);
#pragma unroll
  for(int i=0;i<8;i++) prow[tid+i*256] = f2b(e[i]*inv);
}

// ---------- router: fp32 LN + logits + sigmoid + top-2 -> combine [4096][8] ----------
__global__ __launch_bounds__(64) void router_kernel(const float* __restrict__ x1,
    const float* __restrict__ w, const float* __restrict__ rw,
    const float* __restrict__ bias, float* __restrict__ comb){
  const int t = blockIdx.x, lane = threadIdx.x;
  const float* xr = x1 + (size_t)t*1024;
  float xv[16]; float s=0.f;
#pragma unroll
  for(int i=0;i<16;i++){ xv[i] = xr[lane + i*64]; s += xv[i]; }
  for(int m=32;m;m>>=1) s += __shfl_xor(s,m);
  const float mean = s*(1.f/1024.f);
  float s2=0.f;
#pragma unroll
  for(int i=0;i<16;i++){ float d=xv[i]-mean; s2 += d*d; }
  for(int m=32;m;m>>=1) s2 += __shfl_xor(s2,m);
  const float inv = rsqrtf(s2*(1.f/1024.f)+1e-5f);
  float acc[7]={0,0,0,0,0,0,0};
#pragma unroll
  for(int i=0;i<16;i++){
    const int idx = lane + i*64;
    const float hn = (xv[i]-mean)*inv*w[idx];
#pragma unroll
    for(int e=0;e<7;e++) acc[e] += hn * rw[e*1024+idx];
  }
#pragma unroll
  for(int e=0;e<7;e++)
    for(int m=32;m;m>>=1) acc[e] += __shfl_xor(acc[e],m);
  if(lane==0){
    float p[7];
#pragma unroll
    for(int e=0;e<7;e++) p[e] = 1.f/(1.f+expf(-(acc[e]+bias[e])));
    int i1=0;
#pragma unroll
    for(int e=1;e<7;e++) if(p[e]>p[i1]) i1=e;       // ties -> lowest index, matches top_k
    int i2=(i1==0)?1:0;
#pragma unroll
    for(int e=0;e<7;e++) if(e!=i1 && p[e]>p[i2]) i2=e;
    float o[8]={0,0,0,0,0,0,0,0};
    o[i1]=p[i1]; o[i2]=p[i2];
#pragma unroll
    for(int e=0;e<8;e++) comb[(size_t)t*8+e]=o[e];
  }
}

// ---------- m97-style 128x128 bf16 MFMA GEMM, C[m][n] = sum_k A[m][k]*W[n][k] ----------
// EPI: 0 Cf=acc*sc | 1 Cb=bf16(acc) | 2 Cf=aux+acc | 3 Cb=bf16(silu(aux)*acc)
//      4 Cf+=rs[m*8]*acc | 5 transposed bf16 store vT[b][n][t] (hardcoded 2048x1024 per batch)
template<int EPI>
__global__ __launch_bounds__(256,2) void gemm_bt(
    const u16* __restrict__ A, const u16* __restrict__ Bw,
    int M, int N, int K,
    float* __restrict__ Cf, u16* __restrict__ Cb,
    const float* __restrict__ aux, const float* __restrict__ rs,
    float sc, int ldc)
{
  __shared__ u16 lA[128*64];
  __shared__ u16 lB[128*64];
  const int tid = threadIdx.x;
  const int m0 = blockIdx.y*128, n0 = blockIdx.x*128;
  const int wid = tid>>6, lane = tid&63;
  const int wm = wid>>1, wn = wid&1;
  const int lr = lane&15, lk = lane>>4;

  f32x4v acc[4][4];
#pragma unroll
  for(int i=0;i<4;i++)
#pragma unroll
    for(int j=0;j<4;j++) acc[i][j] = (f32x4v){0.f,0.f,0.f,0.f};

  const int selem = tid*8;          // staging: 256 thr x 16B = 4KB per issue, 4 issues/tile
  const int srow  = tid>>3;
  const int scol  = (tid&7)*8;
  const u16* Ab = A  + (size_t)(m0+srow)*K + scol;
  const u16* Bb = Bw + (size_t)(n0+srow)*K + scol;

  for(int k0=0;k0<K;k0+=64){
#pragma unroll
    for(int is=0;is<4;is++){
      __builtin_amdgcn_global_load_lds(
        (const __attribute__((address_space(1))) void*)(Ab + k0 + (size_t)is*32*K),
        (__attribute__((address_space(3))) void*)(&lA[is*2048 + selem]), 16, 0, 0);
      __builtin_amdgcn_global_load_lds(
        (const __attribute__((address_space(1))) void*)(Bb + k0 + (size_t)is*32*K),
        (__attribute__((address_space(3))) void*)(&lB[is*2048 + selem]), 16, 0, 0);
    }
    __syncthreads();
#pragma unroll
    for(int kk=0;kk<64;kk+=32){
      bf16x8 av[4], bv[4];
#pragma unroll
      for(int i=0;i<4;i++) av[i] = *(bf16x8*)&lA[(wm*64+i*16+lr)*64 + kk + lk*8];
#pragma unroll
      for(int j=0;j<4;j++) bv[j] = *(bf16x8*)&lB[(wn*64+j*16+lr)*64 + kk + lk*8];
#pragma unroll
      for(int i=0;i<4;i++)
#pragma unroll
        for(int j=0;j<4;j++)
          acc[i][j] = __builtin_amdgcn_mfma_f32_16x16x32_bf16(av[i], bv[j], acc[i][j], 0,0,0);
    }
    __syncthreads();
  }

#pragma unroll
  for(int i=0;i<4;i++){
    const int rb = m0 + wm*64 + i*16 + lk*4;     // C/D: row=(lane>>4)*4+reg, col=lane&15
#pragma unroll
    for(int j=0;j<4;j++){
      const int col = n0 + wn*64 + j*16 + lr;
      if (EPI==5){
        const int bb = rb>>11, trow = rb&2047;
        ushort4 o;
        o.x=f2b(acc[i][j][0]); o.y=f2b(acc[i][j][1]);
        o.z=f2b(acc[i][j][2]); o.w=f2b(acc[i][j][3]);
        *(ushort4*)(Cb + ((size_t)((bb<<10)+col))*2048 + trow) = o;
      } else {
#pragma unroll
        for(int r=0;r<4;r++){
          const size_t idx = (size_t)(rb+r)*ldc + col;
          const float v = acc[i][j][r];
          if (EPI==0) Cf[idx] = v*sc;
          else if (EPI==1) Cb[idx] = f2b(v);
          else if (EPI==2) Cf[idx] = aux[idx] + v;
          else if (EPI==3){ const float g=aux[idx]; const float sg=g/(1.f+expf(-g));
                            Cb[idx]=f2b(sg*v); }
          else if (EPI==4) Cf[idx] += rs[(size_t)(rb+r)*8] * v;
        }
      }
    }
  }
}

static void run_gemm(int epi, const u16* A, const u16* B, int M,int N,int K,
                     float* Cf, u16* Cb, const float* aux, const float* rs,
                     float sc, int ldc, hipStream_t st){
  dim3 g((unsigned)(N/128),(unsigned)(M/128)), blk(256);
  switch(epi){
    case 0: gemm_bt<0><<<g,blk,0,st>>>(A,B,M,N,K,Cf,Cb,aux,rs,sc,ldc); break;
    case 1: gemm_bt<1><<<g,blk,0,st>>>(A,B,M,N,K,Cf,Cb,aux,rs,sc,ldc); break;
    case 2: gemm_bt<2><<<g,blk,0,st>>>(A,B,M,N,K,Cf,Cb,aux,rs,sc,ldc); break;
    case 3: gemm_bt<3><<<g,blk,0,st>>>(A,B,M,N,K,Cf,Cb,aux,rs,sc,ldc); break;
    case 4: gemm_bt<4><<<g,blk,0,st>>>(A,B,M,N,K,Cf,Cb,aux,rs,sc,ldc); break;
    case 5: gemm_bt<5><<<g,blk,0,st>>>(A,B,M,N,K,Cf,Cb,aux,rs,sc,ldc); break;
  }
}

// ---------- orchestration ----------
extern "C" void kernel_launch(void* const* d_in, const int* in_sizes, int n_in,
                              void* d_out, int out_size, void* d_ws, size_t ws_size,
                              hipStream_t stream){
  (void)in_sizes; (void)n_in; (void)out_size;
  const float* x      = (const float*)d_in[0];
  const float* ln1w   = (const float*)d_in[1];
  const float* ln2w   = (const float*)d_in[2];
  const float* kvd    = (const float*)d_in[3];
  const float* qd     = (const float*)d_in[4];
  // d_in[5] k_proj_u, d_in[6] q_proj_u: dead in reference (rope outputs overwrite q,k)
  const float* vu     = (const float*)d_in[7];
  const float* ropek  = (const float*)d_in[8];
  const float* ropeq  = (const float*)d_in[9];
  const float* oproj  = (const float*)d_in[10];
  const float* routerw= (const float*)d_in[11];
  const float* rbias  = (const float*)d_in[12];
  const float* shg    = (const float*)d_in[13];
  const float* shu    = (const float*)d_in[14];
  const float* shd    = (const float*)d_in[15];
  const float* exg    = (const float*)d_in[16];
  const float* exu    = (const float*)d_in[17];
  const float* exd    = (const float*)d_in[18];
  float* out = (float*)d_out;

  char* wsp = (char*)d_ws; size_t off = 0;
  auto alloc = [&](size_t bytes)->void*{ void* p = wsp+off; off += (bytes+255)&~(size_t)255; return p; };
  // bf16 weights
  u16* wb_kvd = (u16*)alloc((size_t)262144*2);
  u16* wb_qd  = (u16*)alloc((size_t)262144*2);
  u16* wb_vu  = (u16*)alloc((size_t)262144*2);
  u16* wb_rk  = (u16*)alloc((size_t)1048576*2);
  u16* wb_rq  = (u16*)alloc((size_t)262144*2);
  u16* wb_o   = (u16*)alloc((size_t)1048576*2);
  u16* wb_shg = (u16*)alloc((size_t)2097152*2);
  u16* wb_shu = (u16*)alloc((size_t)2097152*2);
  u16* wb_shd = (u16*)alloc((size_t)2097152*2);
  u16* wb_exg = (u16*)alloc((size_t)14680064*2);
  u16* wb_exu = (u16*)alloc((size_t)14680064*2);
  u16* wb_exd = (u16*)alloc((size_t)14680064*2);
  // activations
  u16* h_b  = (u16*)alloc((size_t)4194304*2);   // ln1 out
  u16* kvl  = (u16*)alloc((size_t)1048576*2);   // [4096][256]
  u16* ql   = (u16*)alloc((size_t)1048576*2);
  u16* vT   = (u16*)alloc((size_t)4194304*2);   // [2][1024][2048] V^T
  u16* q_ro = (u16*)alloc((size_t)4194304*2);   // q_r -> roped in place
  u16* k_ro = (u16*)alloc((size_t)4194304*2);
  u16* y_b  = (u16*)alloc((size_t)4194304*2);   // attn out
  float* x1 = (float*)alloc((size_t)4194304*4); // residual 1
  u16* h2_b = (u16*)alloc((size_t)4194304*2);   // ln2 out
  float* comb = (float*)alloc((size_t)4096*8*4);
  float* gS  = (float*)alloc((size_t)4096*2048*4); // gate fp32 / attn scores (reused)
  u16* aP    = (u16*)alloc((size_t)4096*2048*2);   // silu*up bf16 / attn probs (reused)
  if (off > ws_size) return;  // workspace too small -> loud failure, revisit layout

  auto cvt = [&](const float* s, u16* d, int n){
    cvt_f32_bf16<<<dim3((unsigned)(n/1024)),dim3(256),0,stream>>>(s,d,n);
  };
  cvt(kvd, wb_kvd, 262144);  cvt(qd, wb_qd, 262144);   cvt(vu, wb_vu, 262144);
  cvt(ropek, wb_rk, 1048576); cvt(ropeq, wb_rq, 262144); cvt(oproj, wb_o, 1048576);
  cvt(shg, wb_shg, 2097152); cvt(shu, wb_shu, 2097152); cvt(shd, wb_shd, 2097152);
  cvt(exg, wb_exg, 14680064); cvt(exu, wb_exu, 14680064); cvt(exd, wb_exd, 14680064);

  // ---- attention ----
  ln_kernel<<<dim3(4096),dim3(256),0,stream>>>(x, ln1w, h_b);
  run_gemm(1, h_b, wb_kvd, 4096, 256,1024, nullptr, kvl, nullptr,nullptr, 1.f, 256, stream);
  run_gemm(1, h_b, wb_qd,  4096, 256,1024, nullptr, ql,  nullptr,nullptr, 1.f, 256, stream);
  run_gemm(5, kvl, wb_vu,  4096,1024, 256, nullptr, vT,  nullptr,nullptr, 1.f, 0,   stream);
  run_gemm(1, ql,  wb_rq,  4096,1024, 256, nullptr, q_ro,nullptr,nullptr, 1.f, 1024,stream);
  run_gemm(1, h_b, wb_rk,  4096,1024,1024, nullptr, k_ro,nullptr,nullptr, 1.f, 1024,stream);
  rope_kernel<<<dim3(4096),dim3(256),0,stream>>>(q_ro, k_ro);
  for(int b=0;b<2;b++)
    run_gemm(0, q_ro+(size_t)b*2097152, k_ro+(size_t)b*2097152, 2048,2048,1024,
             gS+(size_t)b*4194304, nullptr, nullptr,nullptr, 1.f, 2048, stream);
  softmax_kernel<<<dim3(2048,2),dim3(256),0,stream>>>(gS, aP);
  for(int b=0;b<2;b++)
    run_gemm(1, aP+(size_t)b*4194304, vT+(size_t)b*2097152, 2048,1024,2048,
             nullptr, y_b+(size_t)b*2097152, nullptr,nullptr, 1.f, 1024, stream);
  run_gemm(2, y_b, wb_o, 4096,1024,1024, x1, nullptr, x, nullptr, 1.f, 1024, stream);

  // ---- MoE ----
  ln_kernel<<<dim3(4096),dim3(256),0,stream>>>(x1, ln2w, h2_b);
  router_kernel<<<dim3(4096),dim3(64),0,stream>>>(x1, ln2w, routerw, rbias, comb);
  // shared expert: out = x1 + silu(h2@g^T)*(h2@u^T) @ d^T
  run_gemm(0, h2_b, wb_shg, 4096,2048,1024, gS, nullptr, nullptr,nullptr, 1.f, 2048, stream);
  run_gemm(3, h2_b, wb_shu, 4096,2048,1024, nullptr, aP, gS, nullptr, 1.f, 2048, stream);
  run_gemm(2, aP,   wb_shd, 4096,1024,2048, out, nullptr, x1, nullptr, 1.f, 1024, stream);
  // routed experts (dense for round 0; combine weight zero for unselected)
  for(int e=0;e<7;e++){
    run_gemm(0, h2_b, wb_exg+(size_t)e*2097152, 4096,2048,1024, gS, nullptr, nullptr,nullptr, 1.f, 2048, stream);
    run_gemm(3, h2_b, wb_exu+(size_t)e*2097152, 4096,2048,1024, nullptr, aP, gS, nullptr, 1.f, 2048, stream);
    run_gemm(4, aP,   wb_exd+(size_t)e*2097152, 4096,1024,2048, out, nullptr, nullptr, comb+e, 1.f, 1024, stream);
  }
}

// Round 2
// 1057.349 us; speedup vs baseline: 1.5175x; 1.5175x over previous
//
#include <hip/hip_runtime.h>
#include <math.h>

// ---------- small helpers ----------
#define DEVI static __device__ __forceinline__
typedef __bf16 bf16x8 __attribute__((ext_vector_type(8)));
typedef float  f32x4v __attribute__((ext_vector_type(4)));
typedef unsigned short u16;

DEVI float b2f(u16 u){ union{unsigned int i; float f;} v; v.i=((unsigned int)u)<<16; return v.f; }
DEVI u16 f2b(float f){ union{float f; unsigned int i;} v; v.f=f;
                       unsigned int r=v.i+0x7FFFu+((v.i>>16)&1u); return (u16)(r>>16); }

#define SLOTCAP 9216   // 72 row-blocks of 128; max padded slots = 8192 + 7*127 = 9081

// ---------- fp32 -> bf16 convert ----------
__global__ __launch_bounds__(256) void cvt_f32_bf16(const float* __restrict__ s,
                                                    u16* __restrict__ d, int n){
  int i = (blockIdx.x*256 + threadIdx.x)*4;
  if (i < n){
    float4 v = *(const float4*)(s+i);
    ushort4 o; o.x=f2b(v.x); o.y=f2b(v.y); o.z=f2b(v.z); o.w=f2b(v.w);
    *(ushort4*)(d+i) = o;
  }
}

// ---------- LayerNorm: fp32 row [1024] -> bf16 ----------
__global__ __launch_bounds__(256) void ln_kernel(const float* __restrict__ x,
                                                 const float* __restrict__ w,
                                                 u16* __restrict__ ob){
  const int row = blockIdx.x, tid = threadIdx.x;
  const float* xr = x + (size_t)row*1024;
  float4 v = *(const float4*)(xr + tid*4);
  float s = v.x+v.y+v.z+v.w;
  for(int m=32;m;m>>=1) s += __shfl_xor(s,m);
  __shared__ float r0[4], r1[4];
  const int wid = tid>>6, lane = tid&63;
  if(!lane) r0[wid]=s;
  __syncthreads();
  const float mean = (r0[0]+r0[1]+r0[2]+r0[3])*(1.f/1024.f);
  float d0=v.x-mean,d1=v.y-mean,d2=v.z-mean,d3=v.w-mean;
  float s2 = d0*d0+d1*d1+d2*d2+d3*d3;
  for(int m=32;m;m>>=1) s2 += __shfl_xor(s2,m);
  if(!lane) r1[wid]=s2;
  __syncthreads();
  const float inv = rsqrtf((r1[0]+r1[1]+r1[2]+r1[3])*(1.f/1024.f) + 1e-5f);
  float4 wv = *(const float4*)(w + tid*4);
  ushort4 o; o.x=f2b(d0*inv*wv.x); o.y=f2b(d1*inv*wv.y);
  o.z=f2b(d2*inv*wv.z); o.w=f2b(d3*inv*wv.w);
  *(ushort4*)(ob + (size_t)row*1024 + tid*4) = o;
}

// ---------- RoPE in-place on bf16 q,k rows ----------
__global__ __launch_bounds__(256) void rope_kernel(u16* __restrict__ q, u16* __restrict__ k){
  const int row = blockIdx.x;            // 0..4095  (b*2048 + t)
  const int t = row & 2047;
  u16* qr = q + (size_t)row*1024;
  u16* kr = k + (size_t)row*1024;
  for (int dd = threadIdx.x; dd < 512; dd += 256){
    const float freq = exp2f(-(float)dd * (13.287712379549449f/512.0f));
    const float ang = (float)t * freq;
    float sn, cs; sincosf(ang, &sn, &cs);
    float a = b2f(qr[dd]), b = b2f(qr[dd+512]);
    qr[dd]     = f2b(a*cs - b*sn);
    qr[dd+512] = f2b(b*cs + a*sn);
    float ka = b2f(kr[dd]), kb = b2f(kr[dd+512]);
    kr[dd]     = f2b(ka*cs - kb*sn);
    kr[dd+512] = f2b(kb*cs + ka*sn);
  }
}

// ---------- causal softmax row kernel: S fp32 [b][t][2048] -> P bf16 ----------
__global__ __launch_bounds__(256) void softmax_kernel(const float* __restrict__ S,
                                                      u16* __restrict__ P){
  const int t = blockIdx.x, b = blockIdx.y, tid = threadIdx.x;
  const float* srow = S + ((size_t)b*2048 + t)*2048;
  u16* prow = P + ((size_t)b*2048 + t)*2048;
  const float scale = 0.03125f;  // 1/sqrt(1024)
  float e[8]; float mx = -INFINITY;
#pragma unroll
  for(int i=0;i<8;i++){
    int c = tid + i*256;
    float v = (c<=t) ? srow[c]*scale : -INFINITY;
    e[i]=v; mx = fmaxf(mx, v);
  }
  for(int m=32;m;m>>=1) mx = fmaxf(mx, __shfl_xor(mx,m));
  __shared__ float r0[4], r1[4];
  const int wid=tid>>6, lane=tid&63;
  if(!lane) r0[wid]=mx;
  __syncthreads();
  mx = fmaxf(fmaxf(r0[0],r0[1]), fmaxf(r0[2],r0[3]));
  float s=0.f;
#pragma unroll
  for(int i=0;i<8;i++){ float v = (e[i]==-INFINITY)?0.f:__expf(e[i]-mx); e[i]=v; s+=v; }
  for(int m=32;m;m>>=1) s += __shfl_xor(s,m);
  if(!lane) r1[wid]=s;
  __syncthreads();
  const float inv = 1.f/(r1[0]+r1[1]+r1[2]+r1[3]);
#pragma unroll
  for(int i=0;i<8;i++) prow[tid+i*256] = f2b(e[i]*inv);
}

// ---------- router: fp32 LN + logits + sigmoid + top-2 ----------
__global__ __launch_bounds__(64) void router_kernel(const float* __restrict__ x1,
    const float* __restrict__ w, const float* __restrict__ rw,
    const float* __restrict__ bias,
    int* __restrict__ te, float* __restrict__ tw, int* __restrict__ cnt){
  const int t = blockIdx.x, lane = threadIdx.x;
  const float* xr = x1 + (size_t)t*1024;
  float xv[16]; float s=0.f;
#pragma unroll
  for(int i=0;i<16;i++){ xv[i] = xr[lane + i*64]; s += xv[i]; }
  for(int m=32;m;m>>=1) s += __shfl_xor(s,m);
  const float mean = s*(1.f/1024.f);
  float s2=0.f;
#pragma unroll
  for(int i=0;i<16;i++){ float d=xv[i]-mean; s2 += d*d; }
  for(int m=32;m;m>>=1) s2 += __shfl_xor(s2,m);
  const float inv = rsqrtf(s2*(1.f/1024.f)+1e-5f);
  float acc[7]={0,0,0,0,0,0,0};
#pragma unroll
  for(int i=0;i<16;i++){
    const int idx = lane + i*64;
    const float hn = (xv[i]-mean)*inv*w[idx];
#pragma unroll
    for(int e=0;e<7;e++) acc[e] += hn * rw[e*1024+idx];
  }
#pragma unroll
  for(int e=0;e<7;e++)
    for(int m=32;m;m>>=1) acc[e] += __shfl_xor(acc[e],m);
  if(lane==0){
    float p[7];
#pragma unroll
    for(int e=0;e<7;e++) p[e] = 1.f/(1.f+expf(-(acc[e]+bias[e])));
    int i1=0;
#pragma unroll
    for(int e=1;e<7;e++) if(p[e]>p[i1]) i1=e;       // ties -> lowest index, matches top_k
    int i2=(i1==0)?1:0;
#pragma unroll
    for(int e=0;e<7;e++) if(e!=i1 && p[e]>p[i2]) i2=e;
    te[t*2]=i1; te[t*2+1]=i2; tw[t*2]=p[i1]; tw[t*2+1]=p[i2];
    atomicAdd(&cnt[i1],1); atomicAdd(&cnt[i2],1);
  }
}

// ---------- MoE bookkeeping ----------
__global__ void zero_kernel(int* __restrict__ cnt, int* __restrict__ fill){
  int t = threadIdx.x; if (t<7){ cnt[t]=0; fill[t]=0; }
}

__global__ __launch_bounds__(256) void prep_kernel(const int* __restrict__ cnt,
    int* __restrict__ base, int* __restrict__ ntot,
    int* __restrict__ stok, float* __restrict__ sw, int* __restrict__ eblk){
  __shared__ int sb[8];
  const int tid = threadIdx.x;
  if (tid==0){
    int o=0;
    for(int e=0;e<7;e++){ sb[e]=o; base[e]=o; o += (cnt[e]+127)&~127; }
    sb[7]=o; *ntot=o;
  }
  __syncthreads();
  for(int e=0;e<7;e++){               // pad slots -> token 0, weight 0
    const int s = sb[e]+cnt[e], en = sb[e+1];
    for(int i=s+tid; i<en; i+=256){ stok[i]=0; sw[i]=0.f; }
  }
  for(int b=tid; b<SLOTCAP/128; b+=256){  // row-block -> expert id
    const int rowst = b*128; int e=6;
#pragma unroll
    for(int q=0;q<7;q++) if (rowst < sb[q+1]){ e=q; break; }
    eblk[b]=e;
  }
}

__global__ __launch_bounds__(256) void scatter_kernel(const int* __restrict__ te,
    const float* __restrict__ tw, const int* __restrict__ base,
    int* __restrict__ fill, int* __restrict__ stok, float* __restrict__ sw){
  const int t = blockIdx.x*256 + threadIdx.x;
  if (t >= 4096) return;
#pragma unroll
  for(int k=0;k<2;k++){
    const int e = te[t*2+k];
    const int s = base[e] + atomicAdd(&fill[e],1);
    stok[s] = t; sw[s] = tw[t*2+k];
  }
}

// ---------- m97-style 128x128 bf16 MFMA GEMM, C[m][n] = sum_k A[m][k]*W[n][k] ----------
// EPI: 0 Cf=acc*sc | 1 Cb=bf16(acc) | 2 Cf=aux+acc | 5 transposed bf16 V^T store
//      6 atomicAdd(out[stok[m]][col], sw[m]*acc) | 7 Cb=bf16(silu(acc)*bf16aux) in-place
template<int EPI>
__global__ __launch_bounds__(256,2) void gemm_bt(
    const u16* __restrict__ A, const u16* __restrict__ Bw,
    int K,
    float* __restrict__ Cf, u16* __restrict__ Cb,
    const float* __restrict__ aux,
    const int* __restrict__ gidx, const int* __restrict__ stok,
    const float* __restrict__ sw, const int* __restrict__ ntot,
    const int* __restrict__ eblk, size_t wstride,
    float sc, int ldc)
{
  const int m0 = blockIdx.y*128, n0 = blockIdx.x*128;
  if (ntot && m0 >= *ntot) return;     // sparse: unused padded row-blocks exit

  __shared__ u16 lA[128*64];
  __shared__ u16 lB[128*64];
  const int tid = threadIdx.x;
  const int wid = tid>>6, lane = tid&63;
  const int wm = wid>>1, wn = wid&1;
  const int lr = lane&15, lk = lane>>4;

  f32x4v acc[4][4];
#pragma unroll
  for(int i=0;i<4;i++)
#pragma unroll
    for(int j=0;j<4;j++) acc[i][j] = (f32x4v){0.f,0.f,0.f,0.f};

  const int selem = tid*8;
  const int srow  = tid>>3;
  const int scol  = (tid&7)*8;
  const u16* Bbase = eblk ? (Bw + (size_t)eblk[blockIdx.y]*wstride) : Bw;
  const u16* Ap[4]; const u16* Bp[4];
#pragma unroll
  for(int is=0;is<4;is++){
    const int ar = m0 + srow + is*32;
    const int arow = gidx ? gidx[ar] : ar;
    Ap[is] = A + (size_t)arow*K + scol;
    Bp[is] = Bbase + (size_t)(n0+srow+is*32)*K + scol;
  }

  for(int k0=0;k0<K;k0+=64){
#pragma unroll
    for(int is=0;is<4;is++){
      __builtin_amdgcn_global_load_lds(
        (const __attribute__((address_space(1))) void*)(Ap[is] + k0),
        (__attribute__((address_space(3))) void*)(&lA[is*2048 + selem]), 16, 0, 0);
      __builtin_amdgcn_global_load_lds(
        (const __attribute__((address_space(1))) void*)(Bp[is] + k0),
        (__attribute__((address_space(3))) void*)(&lB[is*2048 + selem]), 16, 0, 0);
    }
    __syncthreads();
#pragma unroll
    for(int kk=0;kk<64;kk+=32){
      bf16x8 av[4], bv[4];
#pragma unroll
      for(int i=0;i<4;i++) av[i] = *(bf16x8*)&lA[(wm*64+i*16+lr)*64 + kk + lk*8];
#pragma unroll
      for(int j=0;j<4;j++) bv[j] = *(bf16x8*)&lB[(wn*64+j*16+lr)*64 + kk + lk*8];
#pragma unroll
      for(int i=0;i<4;i++)
#pragma unroll
        for(int j=0;j<4;j++)
          acc[i][j] = __builtin_amdgcn_mfma_f32_16x16x32_bf16(av[i], bv[j], acc[i][j], 0,0,0);
    }
    __syncthreads();
  }

#pragma unroll
  for(int i=0;i<4;i++){
    const int rb = m0 + wm*64 + i*16 + lk*4;     // C/D: row=(lane>>4)*4+reg, col=lane&15
#pragma unroll
    for(int j=0;j<4;j++){
      const int col = n0 + wn*64 + j*16 + lr;
      if (EPI==5){
        const int bb = rb>>11, trow = rb&2047;
        ushort4 o;
        o.x=f2b(acc[i][j][0]); o.y=f2b(acc[i][j][1]);
        o.z=f2b(acc[i][j][2]); o.w=f2b(acc[i][j][3]);
        *(ushort4*)(Cb + ((size_t)((bb<<10)+col))*2048 + trow) = o;
      } else {
#pragma unroll
        for(int r=0;r<4;r++){
          const int row = rb + r;
          const size_t idx = (size_t)row*ldc + col;
          const float v = acc[i][j][r];
          if (EPI==0) Cf[idx] = v*sc;
          else if (EPI==1) Cb[idx] = f2b(v);
          else if (EPI==2) Cf[idx] = aux[idx] + v;
          else if (EPI==6){
            const float w = sw[row];
            if (w != 0.f) atomicAdd(&Cf[(size_t)stok[row]*1024 + col], w*v);
          }
          else if (EPI==7){
            const u16* ab = (const u16*)aux;
            const float sg = v/(1.f+expf(-v));
            Cb[idx] = f2b(sg * b2f(ab[idx]));
          }
        }
      }
    }
  }
}

static void run_gemm(int epi, const u16* A, const u16* B, int M,int N,int K,
                     float* Cf, u16* Cb, const float* aux,
                     const int* gidx, const int* stok, const float* sw,
                     const int* ntot, const int* eblk, size_t wstride,
                     float sc, int ldc, hipStream_t st){
  dim3 g((unsigned)(N/128),(unsigned)(M/128)), blk(256);
  switch(epi){
    case 0: gemm_bt<0><<<g,blk,0,st>>>(A,B,K,Cf,Cb,aux,gidx,stok,sw,ntot,eblk,wstride,sc,ldc); break;
    case 1: gemm_bt<1><<<g,blk,0,st>>>(A,B,K,Cf,Cb,aux,gidx,stok,sw,ntot,eblk,wstride,sc,ldc); break;
    case 2: gemm_bt<2><<<g,blk,0,st>>>(A,B,K,Cf,Cb,aux,gidx,stok,sw,ntot,eblk,wstride,sc,ldc); break;
    case 5: gemm_bt<5><<<g,blk,0,st>>>(A,B,K,Cf,Cb,aux,gidx,stok,sw,ntot,eblk,wstride,sc,ldc); break;
    case 6: gemm_bt<6><<<g,blk,0,st>>>(A,B,K,Cf,Cb,aux,gidx,stok,sw,ntot,eblk,wstride,sc,ldc); break;
    case 7: gemm_bt<7><<<g,blk,0,st>>>(A,B,K,Cf,Cb,aux,gidx,stok,sw,ntot,eblk,wstride,sc,ldc); break;
  }
}

// ---------- orchestration ----------
extern "C" void kernel_launch(void* const* d_in, const int* in_sizes, int n_in,
                              void* d_out, int out_size, void* d_ws, size_t ws_size,
                              hipStream_t stream){
  (void)in_sizes; (void)n_in; (void)out_size;
  const float* x      = (const float*)d_in[0];
  const float* ln1w   = (const float*)d_in[1];
  const float* ln2w   = (const float*)d_in[2];
  const float* kvd    = (const float*)d_in[3];
  const float* qd     = (const float*)d_in[4];
  const float* vu     = (const float*)d_in[7];
  const float* ropek  = (const float*)d_in[8];
  const float* ropeq  = (const float*)d_in[9];
  const float* oproj  = (const float*)d_in[10];
  const float* routerw= (const float*)d_in[11];
  const float* rbias  = (const float*)d_in[12];
  const float* shg    = (const float*)d_in[13];
  const float* shu    = (const float*)d_in[14];
  const float* shd    = (const float*)d_in[15];
  const float* exg    = (const float*)d_in[16];
  const float* exu    = (const float*)d_in[17];
  const float* exd    = (const float*)d_in[18];
  float* out = (float*)d_out;

  char* wsp = (char*)d_ws; size_t off = 0;
  auto alloc = [&](size_t bytes)->void*{ void* p = wsp+off; off += (bytes+255)&~(size_t)255; return p; };
  // bf16 weights
  u16* wb_kvd = (u16*)alloc((size_t)262144*2);
  u16* wb_qd  = (u16*)alloc((size_t)262144*2);
  u16* wb_vu  = (u16*)alloc((size_t)262144*2);
  u16* wb_rk  = (u16*)alloc((size_t)1048576*2);
  u16* wb_rq  = (u16*)alloc((size_t)262144*2);
  u16* wb_o   = (u16*)alloc((size_t)1048576*2);
  u16* wb_shg = (u16*)alloc((size_t)2097152*2);
  u16* wb_shu = (u16*)alloc((size_t)2097152*2);
  u16* wb_shd = (u16*)alloc((size_t)2097152*2);
  u16* wb_exg = (u16*)alloc((size_t)14680064*2);
  u16* wb_exu = (u16*)alloc((size_t)14680064*2);
  u16* wb_exd = (u16*)alloc((size_t)14680064*2);
  // persistent activations
  u16* h_b  = (u16*)alloc((size_t)4194304*2);   // ln1 out
  u16* kvl  = (u16*)alloc((size_t)1048576*2);
  u16* ql   = (u16*)alloc((size_t)1048576*2);
  u16* vT   = (u16*)alloc((size_t)4194304*2);   // [2][1024][2048] V^T
  u16* q_ro = (u16*)alloc((size_t)4194304*2);
  u16* k_ro = (u16*)alloc((size_t)4194304*2);
  u16* y_b  = (u16*)alloc((size_t)4194304*2);
  float* x1 = (float*)alloc((size_t)4194304*4); // residual 1
  u16* h2_b = (u16*)alloc((size_t)4194304*2);   // ln2 out
  // union scratch: attention {gS fp32 32MB, aP bf16 16MB} / MoE routed {act bf16 37.75MB}
  char* U   = (char*)alloc((size_t)50331648);
  float* gS = (float*)U;
  u16*   aP = (u16*)(U + 33554432);
  u16*  act = (u16*)U;
  // MoE bookkeeping
  int*   te   = (int*)alloc(8192*4);
  float* tw   = (float*)alloc(8192*4);
  int*   cnt  = (int*)alloc(64);
  int*   base = (int*)alloc(64);
  int*   fill = (int*)alloc(64);
  int*   ntot = (int*)alloc(64);
  int*   stok = (int*)alloc(SLOTCAP*4);
  float* sw   = (float*)alloc(SLOTCAP*4);
  int*   eblk = (int*)alloc((SLOTCAP/128)*4);
  if (off > ws_size) return;  // workspace too small -> loud failure

  auto cvt = [&](const float* s, u16* d, int n){
    cvt_f32_bf16<<<dim3((unsigned)(n/1024)),dim3(256),0,stream>>>(s,d,n);
  };
  cvt(kvd, wb_kvd, 262144);  cvt(qd, wb_qd, 262144);   cvt(vu, wb_vu, 262144);
  cvt(ropek, wb_rk, 1048576); cvt(ropeq, wb_rq, 262144); cvt(oproj, wb_o, 1048576);
  cvt(shg, wb_shg, 2097152); cvt(shu, wb_shu, 2097152); cvt(shd, wb_shd, 2097152);
  cvt(exg, wb_exg, 14680064); cvt(exu, wb_exu, 14680064); cvt(exd, wb_exd, 14680064);

  const size_t WST = 2097152;  // per-expert weight stride (F*H = H*F)

  // ---- attention ----
  ln_kernel<<<dim3(4096),dim3(256),0,stream>>>(x, ln1w, h_b);
  run_gemm(1, h_b, wb_kvd, 4096, 256,1024, 0,kvl,0, 0,0,0,0,0,0, 1.f, 256, stream);
  run_gemm(1, h_b, wb_qd,  4096, 256,1024, 0,ql, 0, 0,0,0,0,0,0, 1.f, 256, stream);
  run_gemm(5, kvl, wb_vu,  4096,1024, 256, 0,vT, 0, 0,0,0,0,0,0, 1.f, 0,   stream);
  run_gemm(1, ql,  wb_rq,  4096,1024, 256, 0,q_ro,0,0,0,0,0,0,0, 1.f, 1024,stream);
  run_gemm(1, h_b, wb_rk,  4096,1024,1024, 0,k_ro,0,0,0,0,0,0,0, 1.f, 1024,stream);
  rope_kernel<<<dim3(4096),dim3(256),0,stream>>>(q_ro, k_ro);
  for(int b=0;b<2;b++)
    run_gemm(0, q_ro+(size_t)b*2097152, k_ro+(size_t)b*2097152, 2048,2048,1024,
             gS+(size_t)b*4194304, 0, 0, 0,0,0,0,0,0, 1.f, 2048, stream);
  softmax_kernel<<<dim3(2048,2),dim3(256),0,stream>>>(gS, aP);
  for(int b=0;b<2;b++)
    run_gemm(1, aP+(size_t)b*4194304, vT+(size_t)b*2097152, 2048,1024,2048,
             0, y_b+(size_t)b*2097152, 0, 0,0,0,0,0,0, 1.f, 1024, stream);
  run_gemm(2, y_b, wb_o, 4096,1024,1024, x1, 0, x, 0,0,0,0,0,0, 1.f, 1024, stream);

  // ---- MoE routing ----
  ln_kernel<<<dim3(4096),dim3(256),0,stream>>>(x1, ln2w, h2_b);
  zero_kernel<<<dim3(1),dim3(64),0,stream>>>(cnt, fill);
  router_kernel<<<dim3(4096),dim3(64),0,stream>>>(x1, ln2w, routerw, rbias, te, tw, cnt);
  prep_kernel<<<dim3(1),dim3(256),0,stream>>>(cnt, base, ntot, stok, sw, eblk);
  scatter_kernel<<<dim3(16),dim3(256),0,stream>>>(te, tw, base, fill, stok, sw);

  // ---- shared expert: up -> gate(silu*up) -> down (out = x1 + shared) ----
  run_gemm(1, h2_b, wb_shu, 4096,2048,1024, 0, aP, 0, 0,0,0,0,0,0, 1.f, 2048, stream);
  run_gemm(7, h2_b, wb_shg, 4096,2048,1024, 0, aP, (const float*)aP, 0,0,0,0,0,0, 1.f, 2048, stream);
  run_gemm(2, aP,   wb_shd, 4096,1024,2048, out, 0, x1, 0,0,0,0,0,0, 1.f, 1024, stream);

  // ---- routed experts: grouped gather-GEMMs over padded slot list ----
  run_gemm(1, h2_b, wb_exu, SLOTCAP,2048,1024, 0, act, 0,
           stok, 0,0, ntot, eblk, WST, 1.f, 2048, stream);                  // up (gathered)
  run_gemm(7, h2_b, wb_exg, SLOTCAP,2048,1024, 0, act, (const float*)act,
           stok, 0,0, ntot, eblk, WST, 1.f, 2048, stream);                  // gate*silu in-place
  run_gemm(6, act, wb_exd, SLOTCAP,1024,2048, out, 0, 0,
           0, stok, sw, ntot, eblk, WST, 1.f, 1024, stream);                // down + scatter-add
}

// Round 3
// 953.882 us; speedup vs baseline: 1.6821x; 1.1085x over previous
//
#include <hip/hip_runtime.h>
#include <math.h>

// ---------- small helpers ----------
#define DEVI static __device__ __forceinline__
typedef __bf16 bf16x8 __attribute__((ext_vector_type(8)));
typedef float  f32x4v __attribute__((ext_vector_type(4)));
typedef unsigned short u16;

DEVI float b2f(u16 u){ union{unsigned int i; float f;} v; v.i=((unsigned int)u)<<16; return v.f; }
DEVI u16 f2b(float f){ union{float f; unsigned int i;} v; v.f=f;
                       unsigned int r=v.i+0x7FFFu+((v.i>>16)&1u); return (u16)(r>>16); }

#define SLOTCAP 10240   // 40 row-blocks of 256; max padded = 8192 + 7*255 -> ceil256 <= 9984

// ---------- fp32 -> bf16 convert ----------
__global__ __launch_bounds__(256) void cvt_f32_bf16(const float* __restrict__ s,
                                                    u16* __restrict__ d, int n){
  int i = (blockIdx.x*256 + threadIdx.x)*4;
  if (i < n){
    float4 v = *(const float4*)(s+i);
    ushort4 o; o.x=f2b(v.x); o.y=f2b(v.y); o.z=f2b(v.z); o.w=f2b(v.w);
    *(ushort4*)(d+i) = o;
  }
}

// ---------- LayerNorm: fp32 row [1024] -> bf16 ----------
__global__ __launch_bounds__(256) void ln_kernel(const float* __restrict__ x,
                                                 const float* __restrict__ w,
                                                 u16* __restrict__ ob){
  const int row = blockIdx.x, tid = threadIdx.x;
  const float* xr = x + (size_t)row*1024;
  float4 v = *(const float4*)(xr + tid*4);
  float s = v.x+v.y+v.z+v.w;
  for(int m=32;m;m>>=1) s += __shfl_xor(s,m);
  __shared__ float r0[4], r1[4];
  const int wid = tid>>6, lane = tid&63;
  if(!lane) r0[wid]=s;
  __syncthreads();
  const float mean = (r0[0]+r0[1]+r0[2]+r0[3])*(1.f/1024.f);
  float d0=v.x-mean,d1=v.y-mean,d2=v.z-mean,d3=v.w-mean;
  float s2 = d0*d0+d1*d1+d2*d2+d3*d3;
  for(int m=32;m;m>>=1) s2 += __shfl_xor(s2,m);
  if(!lane) r1[wid]=s2;
  __syncthreads();
  const float inv = rsqrtf((r1[0]+r1[1]+r1[2]+r1[3])*(1.f/1024.f) + 1e-5f);
  float4 wv = *(const float4*)(w + tid*4);
  ushort4 o; o.x=f2b(d0*inv*wv.x); o.y=f2b(d1*inv*wv.y);
  o.z=f2b(d2*inv*wv.z); o.w=f2b(d3*inv*wv.w);
  *(ushort4*)(ob + (size_t)row*1024 + tid*4) = o;
}

// ---------- RoPE in-place on bf16 q,k rows ----------
__global__ __launch_bounds__(256) void rope_kernel(u16* __restrict__ q, u16* __restrict__ k){
  const int row = blockIdx.x;            // 0..4095  (b*2048 + t)
  const int t = row & 2047;
  u16* qr = q + (size_t)row*1024;
  u16* kr = k + (size_t)row*1024;
  for (int dd = threadIdx.x; dd < 512; dd += 256){
    const float freq = exp2f(-(float)dd * (13.287712379549449f/512.0f));
    const float ang = (float)t * freq;
    float sn, cs; sincosf(ang, &sn, &cs);
    float a = b2f(qr[dd]), b = b2f(qr[dd+512]);
    qr[dd]     = f2b(a*cs - b*sn);
    qr[dd+512] = f2b(b*cs + a*sn);
    float ka = b2f(kr[dd]), kb = b2f(kr[dd+512]);
    kr[dd]     = f2b(ka*cs - kb*sn);
    kr[dd+512] = f2b(kb*cs + ka*sn);
  }
}

// ---------- causal softmax row kernel: S fp32 [b][t][2048] -> P bf16 ----------
__global__ __launch_bounds__(256) void softmax_kernel(const float* __restrict__ S,
                                                      u16* __restrict__ P){
  const int t = blockIdx.x, b = blockIdx.y, tid = threadIdx.x;
  const float* srow = S + ((size_t)b*2048 + t)*2048;
  u16* prow = P + ((size_t)b*2048 + t)*2048;
  const float scale = 0.03125f;  // 1/sqrt(1024)
  float e[8]; float mx = -INFINITY;
#pragma unroll
  for(int i=0;i<8;i++){
    int c = tid + i*256;
    float v = (c<=t) ? srow[c]*scale : -INFINITY;
    e[i]=v; mx = fmaxf(mx, v);
  }
  for(int m=32;m;m>>=1) mx = fmaxf(mx, __shfl_xor(mx,m));
  __shared__ float r0[4], r1[4];
  const int wid=tid>>6, lane=tid&63;
  if(!lane) r0[wid]=mx;
  __syncthreads();
  mx = fmaxf(fmaxf(r0[0],r0[1]), fmaxf(r0[2],r0[3]));
  float s=0.f;
#pragma unroll
  for(int i=0;i<8;i++){ float v = (e[i]==-INFINITY)?0.f:__expf(e[i]-mx); e[i]=v; s+=v; }
  for(int m=32;m;m>>=1) s += __shfl_xor(s,m);
  if(!lane) r1[wid]=s;
  __syncthreads();
  const float inv = 1.f/(r1[0]+r1[1]+r1[2]+r1[3]);
#pragma unroll
  for(int i=0;i<8;i++) prow[tid+i*256] = f2b(e[i]*inv);
}

// ---------- router: fp32 LN + logits + sigmoid + top-2 (NO global atomics) ----------
__global__ __launch_bounds__(256) void router_kernel(const float* __restrict__ x1,
    const float* __restrict__ w, const float* __restrict__ rw,
    const float* __restrict__ bias,
    int* __restrict__ te, float* __restrict__ tw){
  const int t = blockIdx.x*4 + (threadIdx.x>>6);
  const int lane = threadIdx.x&63;
  const float* xr = x1 + (size_t)t*1024;
  float4 xv[4]; float s=0.f;
#pragma unroll
  for(int i=0;i<4;i++){ xv[i] = *(const float4*)(xr + i*256 + lane*4);
                        s += xv[i].x+xv[i].y+xv[i].z+xv[i].w; }
  for(int m=32;m;m>>=1) s += __shfl_xor(s,m);
  const float mean = s*(1.f/1024.f);
  float s2=0.f;
#pragma unroll
  for(int i=0;i<4;i++){
    float a=xv[i].x-mean,b=xv[i].y-mean,c=xv[i].z-mean,d=xv[i].w-mean;
    s2 += a*a+b*b+c*c+d*d;
  }
  for(int m=32;m;m>>=1) s2 += __shfl_xor(s2,m);
  const float inv = rsqrtf(s2*(1.f/1024.f)+1e-5f);
  float hn[16];
#pragma unroll
  for(int i=0;i<4;i++){
    const float4 wv = *(const float4*)(w + i*256 + lane*4);
    hn[i*4+0]=(xv[i].x-mean)*inv*wv.x; hn[i*4+1]=(xv[i].y-mean)*inv*wv.y;
    hn[i*4+2]=(xv[i].z-mean)*inv*wv.z; hn[i*4+3]=(xv[i].w-mean)*inv*wv.w;
  }
  float acc[7];
#pragma unroll
  for(int e=0;e<7;e++){
    float a=0.f;
#pragma unroll
    for(int i=0;i<4;i++){
      const float4 rv = *(const float4*)(rw + (size_t)e*1024 + i*256 + lane*4);
      a += hn[i*4+0]*rv.x + hn[i*4+1]*rv.y + hn[i*4+2]*rv.z + hn[i*4+3]*rv.w;
    }
    acc[e]=a;
  }
#pragma unroll
  for(int e=0;e<7;e++)
    for(int m=32;m;m>>=1) acc[e] += __shfl_xor(acc[e],m);
  if(lane==0){
    float p[7];
#pragma unroll
    for(int e=0;e<7;e++) p[e] = 1.f/(1.f+expf(-(acc[e]+bias[e])));
    int i1=0;
#pragma unroll
    for(int e=1;e<7;e++) if(p[e]>p[i1]) i1=e;       // ties -> lowest index, matches top_k
    int i2=(i1==0)?1:0;
#pragma unroll
    for(int e=0;e<7;e++) if(e!=i1 && p[e]>p[i2]) i2=e;
    te[t*2]=i1; te[t*2+1]=i2; tw[t*2]=p[i1]; tw[t*2+1]=p[i2];
  }
}

// ---------- count: one block, LDS histogram ----------
__global__ __launch_bounds__(256) void hist_kernel(const int* __restrict__ te,
                                                   int* __restrict__ cnt){
  __shared__ int h[7];
  const int tid = threadIdx.x;
  if (tid<7) h[tid]=0;
  __syncthreads();
  for(int i=tid;i<8192;i+=256) atomicAdd(&h[te[i]],1);
  __syncthreads();
  if (tid<7) cnt[tid]=h[tid];
}

__global__ __launch_bounds__(256) void prep_kernel(const int* __restrict__ cnt,
    int* __restrict__ base, int* __restrict__ ntot,
    int* __restrict__ stok, float* __restrict__ sw, int* __restrict__ eblk){
  __shared__ int sb[8];
  const int tid = threadIdx.x;
  if (tid==0){
    int o=0;
    for(int e=0;e<7;e++){ sb[e]=o; base[e]=o; o += (cnt[e]+255)&~255; }
    sb[7]=o; *ntot=o;
  }
  __syncthreads();
  for(int e=0;e<7;e++){               // pad slots -> token 0, weight 0
    const int s = sb[e]+cnt[e], en = sb[e+1];
    for(int i=s+tid; i<en; i+=256){ stok[i]=0; sw[i]=0.f; }
  }
  for(int b=tid; b<SLOTCAP/256; b+=256){  // 256-row-block -> expert id
    const int rowst = b*256; int e=6;
#pragma unroll
    for(int q=0;q<7;q++) if (rowst < sb[q+1]){ e=q; break; }
    eblk[b]=e;
  }
}

// ---------- scatter: ONE block, LDS-atomic ranking ----------
__global__ __launch_bounds__(1024) void scatter_kernel(const int* __restrict__ te,
    const float* __restrict__ tw, const int* __restrict__ base,
    int* __restrict__ stok, float* __restrict__ sw){
  __shared__ int lf[7];
  const int tid = threadIdx.x;
  if (tid<7) lf[tid]=0;
  __syncthreads();
  for(int t=tid; t<4096; t+=1024){
#pragma unroll
    for(int k=0;k<2;k++){
      const int e = te[t*2+k];
      const int s = base[e] + atomicAdd(&lf[e],1);
      stok[s] = t; sw[s] = tw[t*2+k];
    }
  }
}

// ================= 256x256 8-phase bf16 GEMM (T2+T3+T4+T5) ====================
// C[m][n] = sum_k A[m][k] * W[n][k].  512 thr = 8 waves (2M x 4N), BK=64,
// LDS 128KB double-buffered, st-swizzle byte ^= ((row&7)<<4), counted vmcnt.
// EPI: 0 Cf=acc (causal skip opt) | 1 Cb=bf16 | 2 Cf=aux+acc
//      6 atomicAdd(Cf[stok[m]*1024+col], sw[m]*acc) | 7 Cb=bf16(silu(acc)*bf16aux)
#define BAR8 asm volatile("s_barrier" ::: "memory")

#define PHASE_Q(LAB, Q, DOSTAGE) { \
  bf16x8 av[2][2]; \
  _Pragma("unroll") for(int m2=0;m2<2;m2++) \
    _Pragma("unroll") for(int ks=0;ks<2;ks++) \
      av[m2][ks] = *(const bf16x8*)((LAB) + aoff[(Q)*2+m2][ks]); \
  DOSTAGE; \
  __builtin_amdgcn_s_setprio(1); \
  _Pragma("unroll") for(int ks=0;ks<2;ks++) \
    _Pragma("unroll") for(int m2=0;m2<2;m2++) \
      _Pragma("unroll") for(int nf=0;nf<4;nf++) \
        acc[(Q)*2+m2][nf] = __builtin_amdgcn_mfma_f32_16x16x32_bf16( \
            av[m2][ks], bv[nf][ks], acc[(Q)*2+m2][nf],0,0,0); \
  __builtin_amdgcn_s_setprio(0); }

#define READ_B(LBB) { \
  _Pragma("unroll") for(int nf=0;nf<4;nf++) \
    _Pragma("unroll") for(int ks=0;ks<2;ks++) \
      bv[nf][ks] = *(const bf16x8*)((LBB) + boff[nf][ks]); }

template<int EPI>
__global__ __launch_bounds__(512,2) void gemm8(
    const u16* __restrict__ A, const u16* __restrict__ Bw, int K, int causal,
    float* __restrict__ Cf, u16* __restrict__ Cb, const float* __restrict__ aux,
    const int* __restrict__ gidx, const int* __restrict__ stok,
    const float* __restrict__ sw, const int* __restrict__ ntot,
    const int* __restrict__ eblk, size_t wstride,
    int ldc, size_t zsa, size_t zsb, size_t zsc)
{
  const int m0 = blockIdx.y*256, n0 = blockIdx.x*256;
  if (ntot && m0 >= *ntot) return;
  if (causal && n0 > m0 + 255) return;
  const int z = blockIdx.z;
  const u16* Ag = A + (size_t)z*zsa;
  const u16* Bg = Bw + (size_t)z*zsb + (eblk ? (size_t)eblk[blockIdx.y]*wstride : 0);

  __shared__ u16 lA[2][16384];
  __shared__ u16 lB[2][16384];

  const int tid = threadIdx.x;
  const int wid = tid>>6, lane = tid&63;
  const int wm = wid>>2, wn = wid&3;
  const int lr = lane&15, lk = lane>>4;

  // staging: thread covers row tid>>3 (in each 64-row group), 16B at pre-swizzled col
  const int srow = tid>>3;
  const int ssw  = ((tid&7)*16) ^ ((srow&7)<<4);   // source byte offset in 128B window
  const u16* Asrc[4]; const u16* Bsrc[4];
#pragma unroll
  for(int is=0; is<4; is++){
    const int ar = m0 + is*64 + srow;
    const int garow = gidx ? gidx[ar] : ar;
    Asrc[is] = Ag + (size_t)garow*K + (ssw>>1);
    Bsrc[is] = Bg + (size_t)(n0 + is*64 + srow)*K + (ssw>>1);
  }
  const int ldsoff = tid*16;  // byte offset (linear dest; is*8192 added per issue)

  auto SB4 = [&](int kt){                       // stage all B of tile kt
    const int c = kt&1; const int kb = kt*64;
#pragma unroll
    for(int is=0; is<4; is++)
      __builtin_amdgcn_global_load_lds(
        (const __attribute__((address_space(1))) void*)(Bsrc[is] + kb),
        (__attribute__((address_space(3))) void*)((char*)&lB[c][0] + is*8192 + ldsoff), 16,0,0);
  };
  auto SA2 = [&](int kt, int p){                // stage A issues {p, p+2}
    const int c = kt&1; const int kb = kt*64;
#pragma unroll
    for(int ii=0; ii<2; ii++){
      const int is = p + ii*2;
      __builtin_amdgcn_global_load_lds(
        (const __attribute__((address_space(1))) void*)(Asrc[is] + kb),
        (__attribute__((address_space(3))) void*)((char*)&lA[c][0] + is*8192 + ldsoff), 16,0,0);
    }
  };

  // read offsets (constant per thread): frag (row, ks) -> swizzled byte address
  int aoff[8][2], boff[4][2];
#pragma unroll
  for(int mf=0; mf<8; mf++){
    const int r = wm*128 + mf*16 + lr;
#pragma unroll
    for(int ks=0; ks<2; ks++){
      const int cb = ks*64 + lk*16;
      aoff[mf][ks] = r*128 + (cb ^ ((r&7)<<4));
    }
  }
#pragma unroll
  for(int nf=0; nf<4; nf++){
    const int r = wn*64 + nf*16 + lr;
#pragma unroll
    for(int ks=0; ks<2; ks++){
      const int cb = ks*64 + lk*16;
      boff[nf][ks] = r*128 + (cb ^ ((r&7)<<4));
    }
  }

  f32x4v acc[8][4];
#pragma unroll
  for(int i=0;i<8;i++)
#pragma unroll
    for(int j=0;j<4;j++) acc[i][j] = (f32x4v){0.f,0.f,0.f,0.f};
  bf16x8 bv[4][2];

  const char* lab0 = (const char*)&lA[0][0]; const char* lab1 = (const char*)&lA[1][0];
  const char* lbb0 = (const char*)&lB[0][0]; const char* lbb1 = (const char*)&lB[1][0];

  const int nt = K>>6;   // K multiple of 128, nt even >= 4 for all uses here
  // prologue: tile0 fully, tile1 B + A{0,2}
  SB4(0); SA2(0,0); SA2(0,1);
  SB4(1); SA2(1,0);

  for(int t=0; t<nt; t+=2){
    const bool s2 = (t+2)<nt, s3 = (t+3)<nt;
    // ph1 : finish staging tile t+1 (A{1,3}); tile t must land; read B + quad0 of buf0
    SA2(t+1,1);
    asm volatile("s_waitcnt vmcnt(8)" ::: "memory");
    BAR8;
    READ_B(lbb0);
    PHASE_Q(lab0, 0, ;);
    BAR8;
    // ph2
    PHASE_Q(lab0, 1, if(s2) SB4(t+2););
    BAR8;
    // ph3
    PHASE_Q(lab0, 2, if(s2) SA2(t+2,0););
    BAR8;
    // ph4
    PHASE_Q(lab0, 3, ;);
    BAR8;
    // ph5 : stage A{1,3} of t+2; tile t+1 must land; read B + quad0 of buf1
    if(s2) SA2(t+2,1);
    if(s2) { asm volatile("s_waitcnt vmcnt(8)" ::: "memory"); }
    else   { asm volatile("s_waitcnt vmcnt(0)" ::: "memory"); }
    BAR8;
    READ_B(lbb1);
    PHASE_Q(lab1, 0, ;);
    BAR8;
    // ph6
    PHASE_Q(lab1, 1, if(s3) SB4(t+3););
    BAR8;
    // ph7
    PHASE_Q(lab1, 2, if(s3) SA2(t+3,0););
    BAR8;
    // ph8
    PHASE_Q(lab1, 3, ;);
    BAR8;
  }

  // ---- epilogue ----
  float* CfZ = Cf ? Cf + (size_t)z*zsc : (float*)0;
  u16*   CbZ = Cb ? Cb + (size_t)z*zsc : (u16*)0;
#pragma unroll
  for(int mf=0; mf<8; mf++){
    const int rb = m0 + wm*128 + mf*16 + lk*4;  // C/D: row=(lane>>4)*4+reg, col=lane&15
#pragma unroll
    for(int nf=0; nf<4; nf++){
      const int col = n0 + wn*64 + nf*16 + lr;
#pragma unroll
      for(int r=0; r<4; r++){
        const int row = rb + r;
        const size_t idx = (size_t)row*ldc + col;
        const float v = acc[mf][nf][r];
        if (EPI==0) CfZ[idx] = v;
        else if (EPI==1) CbZ[idx] = f2b(v);
        else if (EPI==2) CfZ[idx] = aux[idx] + v;
        else if (EPI==6){
          const float w2 = sw[row];
          if (w2 != 0.f) atomicAdd(&Cf[(size_t)stok[row]*1024 + col], w2*v);
        }
        else if (EPI==7){
          const u16* ab = (const u16*)aux;
          const float sg = v/(1.f+expf(-v));
          CbZ[idx] = f2b(sg * b2f(ab[idx]));
        }
      }
    }
  }
}

static void run_gemm8(int epi, const u16* A, const u16* B, int Mblk, int N, int K,
                      float* Cf, u16* Cb, const float* aux,
                      const int* gidx, const int* stok, const float* sw,
                      const int* ntot, const int* eblk, size_t wstride,
                      int ldc, int Z, size_t zsa, size_t zsb, size_t zsc,
                      int causal, hipStream_t st){
  dim3 g((unsigned)(N/256),(unsigned)Mblk,(unsigned)Z), blk(512);
  switch(epi){
    case 0: gemm8<0><<<g,blk,0,st>>>(A,B,K,causal,Cf,Cb,aux,gidx,stok,sw,ntot,eblk,wstride,ldc,zsa,zsb,zsc); break;
    case 1: gemm8<1><<<g,blk,0,st>>>(A,B,K,causal,Cf,Cb,aux,gidx,stok,sw,ntot,eblk,wstride,ldc,zsa,zsb,zsc); break;
    case 2: gemm8<2><<<g,blk,0,st>>>(A,B,K,causal,Cf,Cb,aux,gidx,stok,sw,ntot,eblk,wstride,ldc,zsa,zsb,zsc); break;
    case 6: gemm8<6><<<g,blk,0,st>>>(A,B,K,causal,Cf,Cb,aux,gidx,stok,sw,ntot,eblk,wstride,ldc,zsa,zsb,zsc); break;
    case 7: gemm8<7><<<g,blk,0,st>>>(A,B,K,causal,Cf,Cb,aux,gidx,stok,sw,ntot,eblk,wstride,ldc,zsa,zsb,zsc); break;
  }
}

// ---------- 128x128 2-phase engine (small shapes: N=256 or K=256) ----------
// EPI: 1 Cb=bf16 | 5 transposed bf16 V^T store [2][1024][2048]
template<int EPI>
__global__ __launch_bounds__(256,2) void gemm_bt(
    const u16* __restrict__ A, const u16* __restrict__ Bw, int K,
    u16* __restrict__ Cb, int ldc)
{
  __shared__ u16 lA[128*64];
  __shared__ u16 lB[128*64];
  const int tid = threadIdx.x;
  const int m0 = blockIdx.y*128, n0 = blockIdx.x*128;
  const int wid = tid>>6, lane = tid&63;
  const int wm = wid>>1, wn = wid&1;
  const int lr = lane&15, lk = lane>>4;

  f32x4v acc[4][4];
#pragma unroll
  for(int i=0;i<4;i++)
#pragma unroll
    for(int j=0;j<4;j++) acc[i][j] = (f32x4v){0.f,0.f,0.f,0.f};

  const int selem = tid*8;
  const int srow  = tid>>3;
  const int scol  = (tid&7)*8;
  const u16* Ab = A  + (size_t)(m0+srow)*K + scol;
  const u16* Bb = Bw + (size_t)(n0+srow)*K + scol;

  for(int k0=0;k0<K;k0+=64){
#pragma unroll
    for(int is=0;is<4;is++){
      __builtin_amdgcn_global_load_lds(
        (const __attribute__((address_space(1))) void*)(Ab + k0 + (size_t)is*32*K),
        (__attribute__((address_space(3))) void*)(&lA[is*2048 + selem]), 16, 0, 0);
      __builtin_amdgcn_global_load_lds(
        (const __attribute__((address_space(1))) void*)(Bb + k0 + (size_t)is*32*K),
        (__attribute__((address_space(3))) void*)(&lB[is*2048 + selem]), 16, 0, 0);
    }
    __syncthreads();
#pragma unroll
    for(int kk=0;kk<64;kk+=32){
      bf16x8 av[4], bv[4];
#pragma unroll
      for(int i=0;i<4;i++) av[i] = *(bf16x8*)&lA[(wm*64+i*16+lr)*64 + kk + lk*8];
#pragma unroll
      for(int j=0;j<4;j++) bv[j] = *(bf16x8*)&lB[(wn*64+j*16+lr)*64 + kk + lk*8];
#pragma unroll
      for(int i=0;i<4;i++)
#pragma unroll
        for(int j=0;j<4;j++)
          acc[i][j] = __builtin_amdgcn_mfma_f32_16x16x32_bf16(av[i], bv[j], acc[i][j], 0,0,0);
    }
    __syncthreads();
  }

#pragma unroll
  for(int i=0;i<4;i++){
    const int rb = m0 + wm*64 + i*16 + lk*4;
#pragma unroll
    for(int j=0;j<4;j++){
      const int col = n0 + wn*64 + j*16 + lr;
      if (EPI==5){
        const int bb = rb>>11, trow = rb&2047;
        ushort4 o;
        o.x=f2b(acc[i][j][0]); o.y=f2b(acc[i][j][1]);
        o.z=f2b(acc[i][j][2]); o.w=f2b(acc[i][j][3]);
        *(ushort4*)(Cb + ((size_t)((bb<<10)+col))*2048 + trow) = o;
      } else {
#pragma unroll
        for(int r=0;r<4;r++) Cb[(size_t)(rb+r)*ldc + col] = f2b(acc[i][j][r]);
      }
    }
  }
}

// ---------- orchestration ----------
extern "C" void kernel_launch(void* const* d_in, const int* in_sizes, int n_in,
                              void* d_out, int out_size, void* d_ws, size_t ws_size,
                              hipStream_t stream){
  (void)in_sizes; (void)n_in; (void)out_size;
  const float* x      = (const float*)d_in[0];
  const float* ln1w   = (const float*)d_in[1];
  const float* ln2w   = (const float*)d_in[2];
  const float* kvd    = (const float*)d_in[3];
  const float* qd     = (const float*)d_in[4];
  const float* vu     = (const float*)d_in[7];
  const float* ropek  = (const float*)d_in[8];
  const float* ropeq  = (const float*)d_in[9];
  const float* oproj  = (const float*)d_in[10];
  const float* routerw= (const float*)d_in[11];
  const float* rbias  = (const float*)d_in[12];
  const float* shg    = (const float*)d_in[13];
  const float* shu    = (const float*)d_in[14];
  const float* shd    = (const float*)d_in[15];
  const float* exg    = (const float*)d_in[16];
  const float* exu    = (const float*)d_in[17];
  const float* exd    = (const float*)d_in[18];
  float* out = (float*)d_out;

  char* wsp = (char*)d_ws; size_t off = 0;
  auto alloc = [&](size_t bytes)->void*{ void* p = wsp+off; off += (bytes+255)&~(size_t)255; return p; };
  // bf16 weights
  u16* wb_kvd = (u16*)alloc((size_t)262144*2);
  u16* wb_qd  = (u16*)alloc((size_t)262144*2);
  u16* wb_vu  = (u16*)alloc((size_t)262144*2);
  u16* wb_rk  = (u16*)alloc((size_t)1048576*2);
  u16* wb_rq  = (u16*)alloc((size_t)262144*2);
  u16* wb_o   = (u16*)alloc((size_t)1048576*2);
  u16* wb_shg = (u16*)alloc((size_t)2097152*2);
  u16* wb_shu = (u16*)alloc((size_t)2097152*2);
  u16* wb_shd = (u16*)alloc((size_t)2097152*2);
  u16* wb_exg = (u16*)alloc((size_t)14680064*2);
  u16* wb_exu = (u16*)alloc((size_t)14680064*2);
  u16* wb_exd = (u16*)alloc((size_t)14680064*2);
  // persistent activations
  u16* h_b  = (u16*)alloc((size_t)4194304*2);   // ln1 out
  u16* kvl  = (u16*)alloc((size_t)1048576*2);
  u16* ql   = (u16*)alloc((size_t)1048576*2);
  u16* vT   = (u16*)alloc((size_t)4194304*2);   // [2][1024][2048] V^T
  u16* q_ro = (u16*)alloc((size_t)4194304*2);
  u16* k_ro = (u16*)alloc((size_t)4194304*2);
  u16* y_b  = (u16*)alloc((size_t)4194304*2);
  float* x1 = (float*)alloc((size_t)4194304*4); // residual 1
  u16* h2_b = (u16*)alloc((size_t)4194304*2);   // ln2 out
  // union scratch, 56MB:
  //   attention: aP bf16 probs @ +0 (16MB), gS fp32 scores @ +16MB (32MB)
  //   MoE:       aP bf16 shared-act @ +0 (16MB), act bf16 expert-act @ +16MB (40MB)
  char* U   = (char*)alloc((size_t)58720256);
  u16*   aP = (u16*)U;
  float* gS = (float*)(U + 16777216);
  u16*  act = (u16*)(U + 16777216);
  // MoE bookkeeping
  int*   te   = (int*)alloc(8192*4);
  float* tw   = (float*)alloc(8192*4);
  int*   cnt  = (int*)alloc(64);
  int*   base = (int*)alloc(64);
  int*   ntot = (int*)alloc(64);
  int*   stok = (int*)alloc(SLOTCAP*4);
  float* sw   = (float*)alloc(SLOTCAP*4);
  int*   eblk = (int*)alloc((SLOTCAP/256)*4);
  if (off > ws_size) return;  // workspace too small -> loud failure

  auto cvt = [&](const float* s, u16* d, int n){
    cvt_f32_bf16<<<dim3((unsigned)(n/1024)),dim3(256),0,stream>>>(s,d,n);
  };
  cvt(kvd, wb_kvd, 262144);  cvt(qd, wb_qd, 262144);   cvt(vu, wb_vu, 262144);
  cvt(ropek, wb_rk, 1048576); cvt(ropeq, wb_rq, 262144); cvt(oproj, wb_o, 1048576);
  cvt(shg, wb_shg, 2097152); cvt(shu, wb_shu, 2097152); cvt(shd, wb_shd, 2097152);
  cvt(exg, wb_exg, 14680064); cvt(exu, wb_exu, 14680064); cvt(exd, wb_exd, 14680064);

  const size_t WST = 2097152;  // per-expert weight stride

  // ---- attention ----
  ln_kernel<<<dim3(4096),dim3(256),0,stream>>>(x, ln1w, h_b);
  gemm_bt<1><<<dim3(2,32),dim3(256),0,stream>>>(h_b, wb_kvd, 1024, kvl, 256);
  gemm_bt<1><<<dim3(2,32),dim3(256),0,stream>>>(h_b, wb_qd,  1024, ql,  256);
  gemm_bt<5><<<dim3(8,32),dim3(256),0,stream>>>(kvl, wb_vu,  256,  vT,  0);
  gemm_bt<1><<<dim3(8,32),dim3(256),0,stream>>>(ql,  wb_rq,  256,  q_ro,1024);
  run_gemm8(1, h_b, wb_rk, 16,1024,1024, 0,k_ro,0, 0,0,0,0,0,0, 1024, 1,0,0,0, 0, stream);
  rope_kernel<<<dim3(4096),dim3(256),0,stream>>>(q_ro, k_ro);
  // QK^T causal, batched over z
  run_gemm8(0, q_ro, k_ro, 8,2048,1024, gS,0,0, 0,0,0,0,0,0, 2048,
            2, 2097152,2097152,4194304, 1, stream);
  softmax_kernel<<<dim3(2048,2),dim3(256),0,stream>>>(gS, aP);
  // P @ V^T, batched
  run_gemm8(1, aP, vT, 8,1024,2048, 0,y_b,0, 0,0,0,0,0,0, 1024,
            2, 4194304,2097152,2097152, 0, stream);
  run_gemm8(2, y_b, wb_o, 16,1024,1024, x1,0,x, 0,0,0,0,0,0, 1024, 1,0,0,0, 0, stream);

  // ---- MoE routing ----
  ln_kernel<<<dim3(4096),dim3(256),0,stream>>>(x1, ln2w, h2_b);
  router_kernel<<<dim3(1024),dim3(256),0,stream>>>(x1, ln2w, routerw, rbias, te, tw);
  hist_kernel<<<dim3(1),dim3(256),0,stream>>>(te, cnt);
  prep_kernel<<<dim3(1),dim3(256),0,stream>>>(cnt, base, ntot, stok, sw, eblk);
  scatter_kernel<<<dim3(1),dim3(1024),0,stream>>>(te, tw, base, stok, sw);

  // ---- shared expert: up -> gate(silu*up) -> down ----
  run_gemm8(1, h2_b, wb_shu, 16,2048,1024, 0,aP,0, 0,0,0,0,0,0, 2048, 1,0,0,0, 0, stream);
  run_gemm8(7, h2_b, wb_shg, 16,2048,1024, 0,aP,(const float*)aP, 0,0,0,0,0,0, 2048, 1,0,0,0, 0, stream);
  run_gemm8(2, aP, wb_shd, 16,1024,2048, out,0,x1, 0,0,0,0,0,0, 1024, 1,0,0,0, 0, stream);

  // ---- routed experts: grouped gather-GEMMs ----
  run_gemm8(1, h2_b, wb_exu, SLOTCAP/256,2048,1024, 0,act,0,
            stok,0,0, ntot, eblk, WST, 2048, 1,0,0,0, 0, stream);
  run_gemm8(7, h2_b, wb_exg, SLOTCAP/256,2048,1024, 0,act,(const float*)act,
            stok,0,0, ntot, eblk, WST, 2048, 1,0,0,0, 0, stream);
  run_gemm8(6, act, wb_exd, SLOTCAP/256,1024,2048, out,0,0,
            0,stok,sw, ntot, eblk, WST, 1024, 1,0,0,0, 0, stream);
}